// Round 16
// baseline (2376.021 us; speedup 1.0000x reference)
//
#include <hip/hip_runtime.h>
#include <stdint.h>

#define MDIM 8192
#define NDIM 4096
#define KDIM 4096

typedef float accf_t __attribute__((ext_vector_type(4)));
typedef short s16x8 __attribute__((ext_vector_type(8)));

typedef const __attribute__((address_space(1))) uint8_t* gas_t;
typedef __attribute__((address_space(3))) uint8_t* las_t;

__device__ __forceinline__ void gload16(const void* g, void* l) {
  __builtin_amdgcn_global_load_lds((gas_t)g, (las_t)l, 16, 0, 0);
}

// round-to-nearest-even f32 -> bf16, packed pair
__device__ __forceinline__ uint32_t pk_bf16(float a, float b) {
  uint32_t ua = __builtin_bit_cast(uint32_t, a);
  uint32_t ub = __builtin_bit_cast(uint32_t, b);
  ua += 0x7fffu + ((ua >> 16) & 1u);
  ub += 0x7fffu + ((ub >> 16) & 1u);
  return (ua >> 16) | (ub & 0xffff0000u);
}

// ---------------- prepass: x (f32) -> bf16 ----------------
__global__ void cvt_x_kernel(const float* __restrict__ x, uint16_t* __restrict__ xb) {
  int64_t e = ((int64_t)blockIdx.x * 256 + threadIdx.x) * 8;
  float4 f0 = *reinterpret_cast<const float4*>(x + e);
  float4 f1 = *reinterpret_cast<const float4*>(x + e + 4);
  uint4 u;
  u.x = pk_bf16(f0.x, f0.y);
  u.y = pk_bf16(f0.z, f0.w);
  u.z = pk_bf16(f1.x, f1.y);
  u.w = pk_bf16(f1.z, f1.w);
  *reinterpret_cast<uint4*>(xb + e) = u;
}

// ------- prepass v2: W^T bf16 [N][K], each quadrant read ONCE, 4 writes -------
__global__ void build_wt2_kernel(const float* __restrict__ Wr, const float* __restrict__ Wi,
                                 const float* __restrict__ Wj, const float* __restrict__ Wk,
                                 uint16_t* __restrict__ wt) {
  __shared__ float t[64][65];
  const int s = blockIdx.z;
  const int kq0 = (blockIdx.x & 15) * 64;
  const int nq0 = blockIdx.y * 64;
  const float* srcs[4] = {Wr, Wi, Wj, Wk};
  const float* W = srcs[s];
  const int prc[4][4]  = {{0,1,2,3}, {0,1,2,3}, {0,1,2,3}, {0,1,2,3}};
  const int pcc[4][4]  = {{0,1,2,3}, {1,0,3,2}, {2,3,0,1}, {3,2,1,0}};
  const float psg[4][4] = {{1.f,1.f,1.f,1.f}, {1.f,-1.f,1.f,-1.f},
                           {1.f,-1.f,-1.f,1.f}, {1.f,1.f,-1.f,-1.f}};
  const int tid = threadIdx.x;
  const int lr = tid >> 6;
  const int lc = tid & 63;
#pragma unroll
  for (int p = 0; p < 16; ++p) {
    int kl = p * 4 + lr;
    t[kl][lc] = W[(int64_t)(kq0 + kl) * 1024 + nq0 + lc];
  }
  __syncthreads();
  const int kb = (tid & 7) * 8;
#pragma unroll
  for (int pl = 0; pl < 4; ++pl) {
    const int k0 = prc[s][pl] * 1024 + kq0;
    const int n0 = pcc[s][pl] * 1024 + nq0;
    const float sg = psg[s][pl];
#pragma unroll
    for (int p = 0; p < 2; ++p) {
      int nl = p * 32 + (tid >> 3);
      uint4 u;
      u.x = pk_bf16(sg * t[kb + 0][nl], sg * t[kb + 1][nl]);
      u.y = pk_bf16(sg * t[kb + 2][nl], sg * t[kb + 3][nl]);
      u.z = pk_bf16(sg * t[kb + 4][nl], sg * t[kb + 5][nl]);
      u.w = pk_bf16(sg * t[kb + 6][nl], sg * t[kb + 7][nl]);
      *reinterpret_cast<uint4*>(wt + (int64_t)(n0 + nl) * KDIM + k0 + kb) = u;
    }
  }
}

// ======= v16: single-buffered 256x256, 2 blocks/CU (inter-block overlap) =======
// BM=BN=256, BK=64, 512 thr (8 waves 2Mx4N), per-wave C 128x64 (16x16x32 MFMA).
// LDS 64KB STATIC (single buffer): halves {H0=A-K0,H1=B-K0,H2=A-K1,H3=B-K1} x 16KB;
// slot-XOR swizzle (0 conflicts, verified R1-R14).
// Sync per K-tile (trivially race-free, no ring): 4 compute phases with NO internal
// barriers (waves skew; buffer is stable) -> BAR (all reads done) -> stage all 4
// halves (8 gload16) -> vmcnt(0) -> BAR. The exposed staging drain is covered by
// the CO-RESIDENT block's compute (m114 mechanism): 64KB LDS + 116 VGPR ->
// 2 blocks/CU (launch_bounds(512,4)). Barriers 8 -> 2 per K-tile.

#define SB __builtin_amdgcn_sched_barrier(0);
#define BAR __builtin_amdgcn_s_barrier();
#define WZ { SB asm volatile("s_waitcnt vmcnt(0)"); SB }

#define ISS1(H, T) {                                                          \
    int64_t ko_ = (int64_t)(T) * 64 + ((H) >> 1) * 32;                        \
    const uint16_t* s0_ = ((H) & 1) ? bSrc0 : aSrc0;                          \
    const uint16_t* s1_ = ((H) & 1) ? bSrc1 : aSrc1;                          \
    uint8_t* d_ = dstW + (H) * 16384;                                         \
    gload16(s0_ + ko_, d_);                                                   \
    gload16(s1_ + ko_, d_ + 8192); }

// One compute phase: 12|8 ds_read_b128 -> lgkm(0) -> 16 MFMA. No barriers.
#define PHS(KH, MH)                                                           \
  {                                                                           \
    if ((MH) == 0) {                                                          \
      _Pragma("unroll")                                                       \
      for (int f = 0; f < 4; ++f)                                             \
        bfr[f] = *(const s16x8*)(Lbuf + (KH) * 32768 + 16384 + boff[f]);      \
    }                                                                         \
    s16x8 afr[4];                                                             \
    _Pragma("unroll")                                                         \
    for (int f = 0; f < 4; ++f)                                               \
      afr[f] = *(const s16x8*)(Lbuf + (KH) * 32768 + aoff[(MH) * 4 + f]);     \
    SB                                                                        \
    asm volatile("s_waitcnt lgkmcnt(0)");                                     \
    SB                                                                        \
    __builtin_amdgcn_s_setprio(1);                                            \
    _Pragma("unroll")                                                         \
    for (int f = 0; f < 4; ++f)                                               \
      _Pragma("unroll")                                                       \
      for (int fn = 0; fn < 4; ++fn)                                          \
        acc[(MH) * 4 + f][fn] = __builtin_amdgcn_mfma_f32_16x16x32_bf16(      \
            afr[f], bfr[fn], acc[(MH) * 4 + f][fn], 0, 0, 0);                 \
    __builtin_amdgcn_s_setprio(0);                                            \
  }

__global__ __launch_bounds__(512, 4)
void qgemm_sb_kernel(const uint16_t* __restrict__ xb, const uint16_t* __restrict__ wt,
                     const float* __restrict__ br, const float* __restrict__ bi,
                     const float* __restrict__ bj, const float* __restrict__ bk,
                     float* __restrict__ out) {
  __shared__ __align__(16) uint8_t Lbuf[65536];
  const int tid = threadIdx.x;
  const int wid = tid >> 6, lane = tid & 63;
  const int kg = lane >> 4, rl = lane & 15;
  const int wm = wid >> 2, wn = wid & 3;

  // XCD-aware bijective swizzle (512 blocks % 8 == 0), full-M grid 32x16 tiles
  const int bid = blockIdx.x;
  const int swz = (bid & 7) * 64 + (bid >> 3);
  const int tn = swz >> 5, tm = swz & 31;
  const int m0 = tm * 256, n0 = tn * 256;

  // staging: thread -> (row, slot); logical k-group pre-swizzled on the global side
  const int arow = tid >> 2, aslot = tid & 3;
  const int ag = aslot ^ ((arow >> 1) & 3);
  const uint16_t* aSrc0 = xb + (int64_t)(m0 + arow) * KDIM + ag * 8;
  const uint16_t* aSrc1 = xb + (int64_t)(m0 + 128 + arow) * KDIM + ag * 8;
  const uint16_t* bSrc0 = wt + (int64_t)(n0 + arow) * KDIM + ag * 8;
  const uint16_t* bSrc1 = wt + (int64_t)(n0 + 128 + arow) * KDIM + ag * 8;
  uint8_t* dstW = Lbuf + wid * 1024;  // wave-uniform LDS dest; HW appends lane*16

  // ds_read fragment offsets (swizzled), within one 16KB half
  int aoff[8], boff[4];
#pragma unroll
  for (int f = 0; f < 8; ++f) {
    int r = wm * 128 + f * 16 + rl;
    aoff[f] = r * 64 + ((kg ^ ((r >> 1) & 3)) << 4);
  }
#pragma unroll
  for (int f = 0; f < 4; ++f) {
    int c = wn * 64 + f * 16 + rl;
    boff[f] = c * 64 + ((kg ^ ((c >> 1) & 3)) << 4);
  }

  accf_t acc[8][4] = {};
  s16x8 bfr[4];

  // prologue: stage tile 0
  ISS1(0, 0) ISS1(1, 0) ISS1(2, 0) ISS1(3, 0)
  WZ
  BAR

  // main: tiles 0..62 compute + stage t+1; tile 63 compute only
  for (int t = 0; t < 63; ++t) {
    PHS(0, 0) PHS(0, 1) PHS(1, 0) PHS(1, 1)
    BAR                       // all reads of tile t complete
    ISS1(0, t + 1) ISS1(1, t + 1) ISS1(2, t + 1) ISS1(3, t + 1)
    WZ                        // tile t+1 landed (only our 8 loads outstanding)
    BAR
  }
  PHS(0, 0) PHS(0, 1) PHS(1, 0) PHS(1, 1)

  // epilogue: Hamilton bias + f32 store
  const float s_i[4] = {-1.f, 1.f, -1.f, 1.f};
  const float s_j[4] = {-1.f, 1.f, 1.f, -1.f};
  const float s_k[4] = {-1.f, -1.f, 1.f, 1.f};
  float bias[4];
#pragma unroll
  for (int fn = 0; fn < 4; ++fn) {
    int col = n0 + wn * 64 + fn * 16 + rl;
    int cc = col >> 10, nq = col & 1023;
    bias[fn] = br[nq] + s_i[cc] * bi[nq] + s_j[cc] * bj[nq] + s_k[cc] * bk[nq];
  }
#pragma unroll
  for (int fm = 0; fm < 8; ++fm) {
    int rowb = m0 + wm * 128 + fm * 16 + kg * 4;
#pragma unroll
    for (int r = 0; r < 4; ++r) {
      float* op = out + (int64_t)(rowb + r) * NDIM + n0 + wn * 64 + rl;
#pragma unroll
      for (int fn = 0; fn < 4; ++fn)
        op[fn * 16] = acc[fm][fn][r] + bias[fn];
    }
  }
}

// ---------------- fallback: R1 128x128 m97-structure GEMM (f32 x from global) ----------------
__global__ __launch_bounds__(256, 3)
void qgemm_kernel(const float* __restrict__ xf, const uint16_t* __restrict__ wt,
                  const float* __restrict__ br, const float* __restrict__ bi,
                  const float* __restrict__ bj, const float* __restrict__ bk,
                  float* __restrict__ out) {
  __shared__ __align__(16) uint16_t Alds[128 * 32];
  __shared__ __align__(16) uint16_t Blds[128 * 32];
  const int tid = threadIdx.x;
  const int wid = tid >> 6, lane = tid & 63;
  const int kg = lane >> 4, rl = lane & 15;
  const int bid = blockIdx.x;
  const int swz = (bid & 7) * 256 + (bid >> 3);
  const int tile_m = swz & 63;
  const int tile_n = swz >> 6;
  const int m0 = tile_m * 128, n0 = tile_n * 128;
  const int wr = wid >> 1, wc = wid & 1;
  const int e0 = tid * 8, e1 = (256 + tid) * 8;
  const int r0 = e0 >> 5, r1 = e1 >> 5;
  const int s0 = (e0 >> 3) & 3, s1 = (e1 >> 3) & 3;
  const int g0 = s0 ^ ((r0 >> 1) & 3);
  const int g1 = s1 ^ ((r1 >> 1) & 3);
  const uint16_t* bp0 = wt + (int64_t)(n0 + r0) * KDIM + g0 * 8;
  const uint16_t* bp1 = wt + (int64_t)(n0 + r1) * KDIM + g1 * 8;
  const float* af0 = xf + (int64_t)(m0 + r0) * KDIM + g0 * 8;
  const float* af1 = xf + (int64_t)(m0 + r1) * KDIM + g1 * 8;
  uint8_t* Ab = (uint8_t*)Alds;
  uint8_t* Bb = (uint8_t*)Blds;
  uint8_t* BbW0 = Bb + wid * 1024;
  uint8_t* BbW1 = Bb + 4096 + wid * 1024;
  uint8_t* aw0 = Ab + e0 * 2;
  uint8_t* aw1 = Ab + e1 * 2;
  int aoff[4], boff[4];
#pragma unroll
  for (int f = 0; f < 4; ++f) {
    int arow = wr * 64 + f * 16 + rl;
    aoff[f] = arow * 64 + ((kg ^ ((arow >> 1) & 3)) << 4);
    int bcol = wc * 64 + f * 16 + rl;
    boff[f] = bcol * 64 + ((kg ^ ((bcol >> 1) & 3)) << 4);
  }
  accf_t acc[4][4] = {};
  for (int kt = 0; kt < KDIM / 32; ++kt) {
    gload16(bp0, BbW0);
    gload16(bp1, BbW1);
    bp0 += 32; bp1 += 32;
    float4 fa = *reinterpret_cast<const float4*>(af0);
    float4 fb = *reinterpret_cast<const float4*>(af0 + 4);
    float4 fc = *reinterpret_cast<const float4*>(af1);
    float4 fd = *reinterpret_cast<const float4*>(af1 + 4);
    uint4 u0, u1;
    u0.x = pk_bf16(fa.x, fa.y); u0.y = pk_bf16(fa.z, fa.w);
    u0.z = pk_bf16(fb.x, fb.y); u0.w = pk_bf16(fb.z, fb.w);
    u1.x = pk_bf16(fc.x, fc.y); u1.y = pk_bf16(fc.z, fc.w);
    u1.z = pk_bf16(fd.x, fd.y); u1.w = pk_bf16(fd.z, fd.w);
    *reinterpret_cast<uint4*>(aw0) = u0;
    *reinterpret_cast<uint4*>(aw1) = u1;
    af0 += 32; af1 += 32;
    __syncthreads();
    s16x8 afr[4], bfr[4];
#pragma unroll
    for (int f = 0; f < 4; ++f) afr[f] = *reinterpret_cast<const s16x8*>(Ab + aoff[f]);
#pragma unroll
    for (int f = 0; f < 4; ++f) bfr[f] = *reinterpret_cast<const s16x8*>(Bb + boff[f]);
#pragma unroll
    for (int fm = 0; fm < 4; ++fm)
#pragma unroll
      for (int fn = 0; fn < 4; ++fn)
        acc[fm][fn] = __builtin_amdgcn_mfma_f32_16x16x32_bf16(afr[fm], bfr[fn], acc[fm][fn], 0, 0, 0);
    __syncthreads();
  }
  const float s_i[4] = {-1.f, 1.f, -1.f, 1.f};
  const float s_j[4] = {-1.f, 1.f, 1.f, -1.f};
  const float s_k[4] = {-1.f, -1.f, 1.f, 1.f};
  float bias[4];
#pragma unroll
  for (int fn = 0; fn < 4; ++fn) {
    int col = n0 + wc * 64 + fn * 16 + rl;
    int cc = col >> 10, nq = col & 1023;
    bias[fn] = br[nq] + s_i[cc] * bi[nq] + s_j[cc] * bj[nq] + s_k[cc] * bk[nq];
  }
#pragma unroll
  for (int fm = 0; fm < 4; ++fm) {
    int rowb = m0 + wr * 64 + fm * 16 + kg * 4;
#pragma unroll
    for (int r = 0; r < 4; ++r) {
      float* op = out + (int64_t)(rowb + r) * NDIM + n0 + wc * 64 + rl;
#pragma unroll
      for (int fn = 0; fn < 4; ++fn)
        op[fn * 16] = acc[fm][fn][r] + bias[fn];
    }
  }
}

// ---------------- emergency fallback (ws too small): naive f32 ----------------
__global__ void naive_q_kernel(const float* __restrict__ x,
                               const float* __restrict__ Wr, const float* __restrict__ Wi,
                               const float* __restrict__ Wj, const float* __restrict__ Wk,
                               const float* __restrict__ br, const float* __restrict__ bi,
                               const float* __restrict__ bj, const float* __restrict__ bk,
                               float* __restrict__ out) {
  const int n = blockIdx.x * 256 + threadIdx.x;
  const int m = blockIdx.y;
  const int cc = n >> 10, nq = n & 1023;
  const int srcsel[16] = {0,1,2,3, 1,0,3,2, 2,3,0,1, 3,2,1,0};
  const float sgntab[16] = {1.f,1.f,1.f,1.f, -1.f,1.f,1.f,-1.f, -1.f,-1.f,1.f,1.f, -1.f,1.f,-1.f,1.f};
  const float s_i[4] = {-1.f,1.f,-1.f,1.f}, s_j[4] = {-1.f,1.f,1.f,-1.f}, s_k[4] = {-1.f,-1.f,1.f,1.f};
  const float* srcs[4] = {Wr, Wi, Wj, Wk};
  float acc = br[nq] + s_i[cc] * bi[nq] + s_j[cc] * bj[nq] + s_k[cc] * bk[nq];
  for (int rc = 0; rc < 4; ++rc) {
    const float* W = srcs[srcsel[rc * 4 + cc]];
    const float sg = sgntab[rc * 4 + cc];
    const float* xp = x + (int64_t)m * KDIM + rc * 1024;
    const float* wp = W + nq;
    float a = 0.f;
    for (int kq = 0; kq < 1024; ++kq) a = fmaf(xp[kq], wp[(int64_t)kq * 1024], a);
    acc += sg * a;
  }
  out[(int64_t)m * NDIM + n] = acc;
}

extern "C" void kernel_launch(void* const* d_in, const int* in_sizes, int n_in,
                              void* d_out, int out_size, void* d_ws, size_t ws_size,
                              hipStream_t stream) {
  const float* x  = (const float*)d_in[0];
  const float* Wr = (const float*)d_in[1];
  const float* Wi = (const float*)d_in[2];
  const float* Wj = (const float*)d_in[3];
  const float* Wk = (const float*)d_in[4];
  const float* br = (const float*)d_in[5];
  const float* bi = (const float*)d_in[6];
  const float* bj = (const float*)d_in[7];
  const float* bk = (const float*)d_in[8];
  float* out = (float*)d_out;

  const size_t WT_BYTES = (size_t)NDIM * KDIM * 2;  // 33.5 MB
  const size_t XB_BYTES = (size_t)MDIM * KDIM * 2;  // 67 MB

  if (ws_size < WT_BYTES) {
    dim3 g(NDIM / 256, MDIM);
    naive_q_kernel<<<g, 256, 0, stream>>>(x, Wr, Wi, Wj, Wk, br, bi, bj, bk, out);
    return;
  }
  uint16_t* wt = (uint16_t*)d_ws;
  build_wt2_kernel<<<dim3(16, 16, 4), 256, 0, stream>>>(Wr, Wi, Wj, Wk, wt);
  if (ws_size >= WT_BYTES + XB_BYTES) {
    uint16_t* xbp = wt + (size_t)NDIM * KDIM;
    cvt_x_kernel<<<(MDIM * (KDIM / 8)) / 256, 256, 0, stream>>>(x, xbp);
    qgemm_sb_kernel<<<512, 512, 0, stream>>>(xbp, wt, br, bi, bj, bk, out);
  } else {
    qgemm_kernel<<<2048, 256, 0, stream>>>(x, wt, br, bi, bj, bk, out);
  }
}

// Round 17
// 291.002 us; speedup vs baseline: 8.1650x; 8.1650x over previous
//
#include <hip/hip_runtime.h>
#include <stdint.h>

#define MDIM 8192
#define NDIM 4096
#define KDIM 4096

typedef float accf_t __attribute__((ext_vector_type(4)));
typedef short s16x8 __attribute__((ext_vector_type(8)));

typedef const __attribute__((address_space(1))) uint8_t* gas_t;
typedef __attribute__((address_space(3))) uint8_t* las_t;

__device__ __forceinline__ void gload16(const void* g, void* l) {
  __builtin_amdgcn_global_load_lds((gas_t)g, (las_t)l, 16, 0, 0);
}

// round-to-nearest-even f32 -> bf16, packed pair
__device__ __forceinline__ uint32_t pk_bf16(float a, float b) {
  uint32_t ua = __builtin_bit_cast(uint32_t, a);
  uint32_t ub = __builtin_bit_cast(uint32_t, b);
  ua += 0x7fffu + ((ua >> 16) & 1u);
  ub += 0x7fffu + ((ub >> 16) & 1u);
  return (ua >> 16) | (ub & 0xffff0000u);
}

// ---------------- prepass: x (f32) -> bf16 ----------------
__global__ void cvt_x_kernel(const float* __restrict__ x, uint16_t* __restrict__ xb) {
  int64_t e = ((int64_t)blockIdx.x * 256 + threadIdx.x) * 8;
  float4 f0 = *reinterpret_cast<const float4*>(x + e);
  float4 f1 = *reinterpret_cast<const float4*>(x + e + 4);
  uint4 u;
  u.x = pk_bf16(f0.x, f0.y);
  u.y = pk_bf16(f0.z, f0.w);
  u.z = pk_bf16(f1.x, f1.y);
  u.w = pk_bf16(f1.z, f1.w);
  *reinterpret_cast<uint4*>(xb + e) = u;
}

// ------- prepass v2: W^T bf16 [N][K], each quadrant read ONCE, 4 writes -------
// Quadrant s placements (rc,cc,sign), from the Hamilton block matrix:
//   s=0 (Wr): (0,0)+ (1,1)+ (2,2)+ (3,3)+
//   s=1 (Wi): (0,1)+ (1,0)- (2,3)+ (3,2)-
//   s=2 (Wj): (0,2)+ (1,3)- (2,0)- (3,1)+
//   s=3 (Wk): (0,3)+ (1,2)+ (2,1)- (3,0)-
__global__ void build_wt2_kernel(const float* __restrict__ Wr, const float* __restrict__ Wi,
                                 const float* __restrict__ Wj, const float* __restrict__ Wk,
                                 uint16_t* __restrict__ wt) {
  __shared__ float t[64][65];
  const int s = blockIdx.z;
  const int kq0 = (blockIdx.x & 15) * 64;
  const int nq0 = blockIdx.y * 64;
  const float* srcs[4] = {Wr, Wi, Wj, Wk};
  const float* W = srcs[s];
  const int prc[4][4]  = {{0,1,2,3}, {0,1,2,3}, {0,1,2,3}, {0,1,2,3}};
  const int pcc[4][4]  = {{0,1,2,3}, {1,0,3,2}, {2,3,0,1}, {3,2,1,0}};
  const float psg[4][4] = {{1.f,1.f,1.f,1.f}, {1.f,-1.f,1.f,-1.f},
                           {1.f,-1.f,-1.f,1.f}, {1.f,1.f,-1.f,-1.f}};
  const int tid = threadIdx.x;
  const int lr = tid >> 6;
  const int lc = tid & 63;
#pragma unroll
  for (int p = 0; p < 16; ++p) {
    int kl = p * 4 + lr;
    t[kl][lc] = W[(int64_t)(kq0 + kl) * 1024 + nq0 + lc];
  }
  __syncthreads();
  const int kb = (tid & 7) * 8;
#pragma unroll
  for (int pl = 0; pl < 4; ++pl) {
    const int k0 = prc[s][pl] * 1024 + kq0;
    const int n0 = pcc[s][pl] * 1024 + nq0;
    const float sg = psg[s][pl];
#pragma unroll
    for (int p = 0; p < 2; ++p) {
      int nl = p * 32 + (tid >> 3);
      uint4 u;
      u.x = pk_bf16(sg * t[kb + 0][nl], sg * t[kb + 1][nl]);
      u.y = pk_bf16(sg * t[kb + 2][nl], sg * t[kb + 3][nl]);
      u.z = pk_bf16(sg * t[kb + 4][nl], sg * t[kb + 5][nl]);
      u.w = pk_bf16(sg * t[kb + 6][nl], sg * t[kb + 7][nl]);
      *reinterpret_cast<uint4*>(wt + (int64_t)(n0 + nl) * KDIM + k0 + kb) = u;
    }
  }
}

// ======= v17 = R14 restored (session best, 291.5 us): R13 race-free ring =======
// Geometry: BM=BN=256, BK=64, 512 thr (8 waves 2Mx4N), per-wave C 128x64.
// LDS 128KB: buf{0,1} x halves {H0=A-K0,H1=B-K0,H2=A-K1,H3=B-K1} x 16KB;
// slot-XOR swizzle (0 conflicts). Race-free ISS ring: every ISS issued the phase
// AFTER its slot's last reader (R13/R14 passed + tripwire-clean).
// NOTE (R16 lesson): launch_bounds(512,2) is mandatory — (512,4) forces the
// allocator into the 64-VGPR bin, spilling acc[8][4] to scratch (6.7 GB writes).

#define SB __builtin_amdgcn_sched_barrier(0);
#define VM6 { asm volatile("s_waitcnt vmcnt(6)"); SB }
#define VM0 { asm volatile("s_waitcnt vmcnt(0)"); SB }

#define ISS(BUF, H, T) {                                                      \
    int64_t ko_ = (int64_t)(T) * 64 + ((H) >> 1) * 32;                        \
    const uint16_t* s0_ = ((H) & 1) ? bSrc0 : aSrc0;                          \
    const uint16_t* s1_ = ((H) & 1) ? bSrc1 : aSrc1;                          \
    uint8_t* d_ = dstW + (BUF) * 65536 + (H) * 16384;                         \
    gload16(s0_ + ko_, d_);                                                   \
    gload16(s1_ + ko_, d_ + 8192); }

#define PH(BUF, KH, MH, ISSUE, LASTVM)                                        \
  {                                                                           \
    if ((MH) == 0) {                                                          \
      _Pragma("unroll")                                                       \
      for (int f = 0; f < 4; ++f)                                             \
        bfr[f] = *(const s16x8*)(ldsb + (BUF) * 65536 + (KH) * 32768 + 16384 + boff[f]); \
    }                                                                         \
    s16x8 afr[4];                                                             \
    _Pragma("unroll")                                                         \
    for (int f = 0; f < 4; ++f)                                               \
      afr[f] = *(const s16x8*)(ldsb + (BUF) * 65536 + (KH) * 32768 + aoff[(MH) * 4 + f]); \
    ISSUE                                                                     \
    __builtin_amdgcn_s_barrier();                                             \
    asm volatile("s_waitcnt lgkmcnt(0)");                                     \
    SB                                                                        \
    if (PRIO) __builtin_amdgcn_s_setprio(1);                                  \
    _Pragma("unroll")                                                         \
    for (int f = 0; f < 4; ++f)                                               \
      _Pragma("unroll")                                                       \
      for (int fn = 0; fn < 4; ++fn)                                          \
        acc[(MH) * 4 + f][fn] = __builtin_amdgcn_mfma_f32_16x16x32_bf16(      \
            afr[f], bfr[fn], acc[(MH) * 4 + f][fn], 0, 0, 0);                 \
    if (PRIO) __builtin_amdgcn_s_setprio(0);                                  \
    LASTVM                                                                    \
    __builtin_amdgcn_s_barrier();                                             \
  }

template <int PRIO>
__global__ __launch_bounds__(512, 2)
void qgemm8_kernel(const uint16_t* __restrict__ xb, const uint16_t* __restrict__ wt,
                   const float* __restrict__ br, const float* __restrict__ bi,
                   const float* __restrict__ bj, const float* __restrict__ bk,
                   float* __restrict__ out, int mbase) {
  extern __shared__ uint8_t ldsb[];
  const int tid = threadIdx.x;
  const int wid = tid >> 6, lane = tid & 63;
  const int kg = lane >> 4, rl = lane & 15;
  const int wm = wid >> 2, wn = wid & 3;

  // XCD-aware bijective swizzle (256 blocks % 8 == 0)
  const int bid = blockIdx.x;
  const int swz = (bid & 7) * 32 + (bid >> 3);
  const int tn = swz >> 4, tm = swz & 15;   // 16 x 16 tiles (half-M dispatch)
  const int m0 = mbase + tm * 256, n0 = tn * 256;

  // staging: thread -> (row, slot); logical k-group pre-swizzled on the global side
  const int arow = tid >> 2, aslot = tid & 3;
  const int ag = aslot ^ ((arow >> 1) & 3);
  const uint16_t* aSrc0 = xb + (int64_t)(m0 + arow) * KDIM + ag * 8;
  const uint16_t* aSrc1 = xb + (int64_t)(m0 + 128 + arow) * KDIM + ag * 8;
  const uint16_t* bSrc0 = wt + (int64_t)(n0 + arow) * KDIM + ag * 8;
  const uint16_t* bSrc1 = wt + (int64_t)(n0 + 128 + arow) * KDIM + ag * 8;
  uint8_t* dstW = ldsb + wid * 1024;  // wave-uniform LDS dest; HW appends lane*16

  // ds_read fragment offsets (swizzled), within one 16KB half
  int aoff[8], boff[4];
#pragma unroll
  for (int f = 0; f < 8; ++f) {
    int r = wm * 128 + f * 16 + rl;
    aoff[f] = r * 64 + ((kg ^ ((r >> 1) & 3)) << 4);
  }
#pragma unroll
  for (int f = 0; f < 4; ++f) {
    int c = wn * 64 + f * 16 + rl;
    boff[f] = c * 64 + ((kg ^ ((c >> 1) & 3)) << 4);
  }

  accf_t acc[8][4] = {};
  s16x8 bfr[4];

  // prologue: tile0 all 4 halves + tile1 {H0,H1,H3} (H2 staged at iter-0 ph0).
  ISS(0, 0, 0) ISS(0, 1, 0) ISS(0, 2, 0) ISS(0, 3, 0)
  ISS(1, 0, 1) ISS(1, 1, 1) ISS(1, 3, 1)
  VM6
  __builtin_amdgcn_s_barrier();

  // main: 31 iters x 2 K-tiles (tiles 0..61); race-free ISS placement
  for (int i = 0; i < 31; ++i) {
    const int t = 2 * i;
    PH(0, 0, 0, ISS(1, 2, t + 1), )      // ph0: buf1.H2 free since prev ph7
    PH(0, 0, 1, ISS(0, 1, t + 2), )      // ph1: buf0.H1 free since ph0
    PH(0, 1, 0, ISS(0, 0, t + 2), )      // ph2: buf0.H0 free since ph1
    PH(0, 1, 1, ISS(0, 3, t + 2), VM6)   // ph3: buf0.H3 free since ph2
    PH(1, 0, 0, ISS(0, 2, t + 2), )      // ph4: buf0.H2 free since ph3
    PH(1, 0, 1, ISS(1, 1, t + 3), )      // ph5: buf1.H1 free since ph4
    PH(1, 1, 0, ISS(1, 0, t + 3), )      // ph6: buf1.H0 free since ph5
    PH(1, 1, 1, ISS(1, 3, t + 3), VM6)   // ph7: buf1.H3 free since ph6
  }
  // tail: tile 62 (buf0) with buf1.H2 staging; then tile 63 (buf1)
  PH(0, 0, 0, ISS(1, 2, 63), )
  PH(0, 0, 1, , )
  PH(0, 1, 0, , )
  PH(0, 1, 1, , VM0)
  PH(1, 0, 0, , )
  PH(1, 0, 1, , )
  PH(1, 1, 0, , )
  PH(1, 1, 1, , )

  // epilogue: Hamilton bias + f32 store
  const float s_i[4] = {-1.f, 1.f, -1.f, 1.f};
  const float s_j[4] = {-1.f, 1.f, 1.f, -1.f};
  const float s_k[4] = {-1.f, -1.f, 1.f, 1.f};
  float bias[4];
#pragma unroll
  for (int fn = 0; fn < 4; ++fn) {
    int col = n0 + wn * 64 + fn * 16 + rl;
    int cc = col >> 10, nq = col & 1023;
    bias[fn] = br[nq] + s_i[cc] * bi[nq] + s_j[cc] * bj[nq] + s_k[cc] * bk[nq];
  }
#pragma unroll
  for (int fm = 0; fm < 8; ++fm) {
    int rowb = m0 + wm * 128 + fm * 16 + kg * 4;
#pragma unroll
    for (int r = 0; r < 4; ++r) {
      float* op = out + (int64_t)(rowb + r) * NDIM + n0 + wn * 64 + rl;
#pragma unroll
      for (int fn = 0; fn < 4; ++fn)
        op[fn * 16] = acc[fm][fn][r] + bias[fn];
    }
  }
}

// ---------------- fallback: R1 128x128 m97-structure GEMM (f32 x from global) ----------------
__global__ __launch_bounds__(256, 3)
void qgemm_kernel(const float* __restrict__ xf, const uint16_t* __restrict__ wt,
                  const float* __restrict__ br, const float* __restrict__ bi,
                  const float* __restrict__ bj, const float* __restrict__ bk,
                  float* __restrict__ out) {
  __shared__ __align__(16) uint16_t Alds[128 * 32];
  __shared__ __align__(16) uint16_t Blds[128 * 32];
  const int tid = threadIdx.x;
  const int wid = tid >> 6, lane = tid & 63;
  const int kg = lane >> 4, rl = lane & 15;
  const int bid = blockIdx.x;
  const int swz = (bid & 7) * 256 + (bid >> 3);
  const int tile_m = swz & 63;
  const int tile_n = swz >> 6;
  const int m0 = tile_m * 128, n0 = tile_n * 128;
  const int wr = wid >> 1, wc = wid & 1;
  const int e0 = tid * 8, e1 = (256 + tid) * 8;
  const int r0 = e0 >> 5, r1 = e1 >> 5;
  const int s0 = (e0 >> 3) & 3, s1 = (e1 >> 3) & 3;
  const int g0 = s0 ^ ((r0 >> 1) & 3);
  const int g1 = s1 ^ ((r1 >> 1) & 3);
  const uint16_t* bp0 = wt + (int64_t)(n0 + r0) * KDIM + g0 * 8;
  const uint16_t* bp1 = wt + (int64_t)(n0 + r1) * KDIM + g1 * 8;
  const float* af0 = xf + (int64_t)(m0 + r0) * KDIM + g0 * 8;
  const float* af1 = xf + (int64_t)(m0 + r1) * KDIM + g1 * 8;
  uint8_t* Ab = (uint8_t*)Alds;
  uint8_t* Bb = (uint8_t*)Blds;
  uint8_t* BbW0 = Bb + wid * 1024;
  uint8_t* BbW1 = Bb + 4096 + wid * 1024;
  uint8_t* aw0 = Ab + e0 * 2;
  uint8_t* aw1 = Ab + e1 * 2;
  int aoff[4], boff[4];
#pragma unroll
  for (int f = 0; f < 4; ++f) {
    int arow = wr * 64 + f * 16 + rl;
    aoff[f] = arow * 64 + ((kg ^ ((arow >> 1) & 3)) << 4);
    int bcol = wc * 64 + f * 16 + rl;
    boff[f] = bcol * 64 + ((kg ^ ((bcol >> 1) & 3)) << 4);
  }
  accf_t acc[4][4] = {};
  for (int kt = 0; kt < KDIM / 32; ++kt) {
    gload16(bp0, BbW0);
    gload16(bp1, BbW1);
    bp0 += 32; bp1 += 32;
    float4 fa = *reinterpret_cast<const float4*>(af0);
    float4 fb = *reinterpret_cast<const float4*>(af0 + 4);
    float4 fc = *reinterpret_cast<const float4*>(af1);
    float4 fd = *reinterpret_cast<const float4*>(af1 + 4);
    uint4 u0, u1;
    u0.x = pk_bf16(fa.x, fa.y); u0.y = pk_bf16(fa.z, fa.w);
    u0.z = pk_bf16(fb.x, fb.y); u0.w = pk_bf16(fb.z, fb.w);
    u1.x = pk_bf16(fc.x, fc.y); u1.y = pk_bf16(fc.z, fc.w);
    u1.z = pk_bf16(fd.x, fd.y); u1.w = pk_bf16(fd.z, fd.w);
    *reinterpret_cast<uint4*>(aw0) = u0;
    *reinterpret_cast<uint4*>(aw1) = u1;
    af0 += 32; af1 += 32;
    __syncthreads();
    s16x8 afr[4], bfr[4];
#pragma unroll
    for (int f = 0; f < 4; ++f) afr[f] = *reinterpret_cast<const s16x8*>(Ab + aoff[f]);
#pragma unroll
    for (int f = 0; f < 4; ++f) bfr[f] = *reinterpret_cast<const s16x8*>(Bb + boff[f]);
#pragma unroll
    for (int fm = 0; fm < 4; ++fm)
#pragma unroll
      for (int fn = 0; fn < 4; ++fn)
        acc[fm][fn] = __builtin_amdgcn_mfma_f32_16x16x32_bf16(afr[fm], bfr[fn], acc[fm][fn], 0, 0, 0);
    __syncthreads();
  }
  const float s_i[4] = {-1.f, 1.f, -1.f, 1.f};
  const float s_j[4] = {-1.f, 1.f, 1.f, -1.f};
  const float s_k[4] = {-1.f, -1.f, 1.f, 1.f};
  float bias[4];
#pragma unroll
  for (int fn = 0; fn < 4; ++fn) {
    int col = n0 + wc * 64 + fn * 16 + rl;
    int cc = col >> 10, nq = col & 1023;
    bias[fn] = br[nq] + s_i[cc] * bi[nq] + s_j[cc] * bj[nq] + s_k[cc] * bk[nq];
  }
#pragma unroll
  for (int fm = 0; fm < 4; ++fm) {
    int rowb = m0 + wr * 64 + fm * 16 + kg * 4;
#pragma unroll
    for (int r = 0; r < 4; ++r) {
      float* op = out + (int64_t)(rowb + r) * NDIM + n0 + wc * 64 + rl;
#pragma unroll
      for (int fn = 0; fn < 4; ++fn)
        op[fn * 16] = acc[fm][fn][r] + bias[fn];
    }
  }
}

// ---------------- emergency fallback (ws too small): naive f32 ----------------
__global__ void naive_q_kernel(const float* __restrict__ x,
                               const float* __restrict__ Wr, const float* __restrict__ Wi,
                               const float* __restrict__ Wj, const float* __restrict__ Wk,
                               const float* __restrict__ br, const float* __restrict__ bi,
                               const float* __restrict__ bj, const float* __restrict__ bk,
                               float* __restrict__ out) {
  const int n = blockIdx.x * 256 + threadIdx.x;
  const int m = blockIdx.y;
  const int cc = n >> 10, nq = n & 1023;
  const int srcsel[16] = {0,1,2,3, 1,0,3,2, 2,3,0,1, 3,2,1,0};
  const float sgntab[16] = {1.f,1.f,1.f,1.f, -1.f,1.f,1.f,-1.f, -1.f,-1.f,1.f,1.f, -1.f,1.f,-1.f,1.f};
  const float s_i[4] = {-1.f,1.f,-1.f,1.f}, s_j[4] = {-1.f,1.f,1.f,-1.f}, s_k[4] = {-1.f,-1.f,1.f,1.f};
  const float* srcs[4] = {Wr, Wi, Wj, Wk};
  float acc = br[nq] + s_i[cc] * bi[nq] + s_j[cc] * bj[nq] + s_k[cc] * bk[nq];
  for (int rc = 0; rc < 4; ++rc) {
    const float* W = srcs[srcsel[rc * 4 + cc]];
    const float sg = sgntab[rc * 4 + cc];
    const float* xp = x + (int64_t)m * KDIM + rc * 1024;
    const float* wp = W + nq;
    float a = 0.f;
    for (int kq = 0; kq < 1024; ++kq) a = fmaf(xp[kq], wp[(int64_t)kq * 1024], a);
    acc += sg * a;
  }
  out[(int64_t)m * NDIM + n] = acc;
}

extern "C" void kernel_launch(void* const* d_in, const int* in_sizes, int n_in,
                              void* d_out, int out_size, void* d_ws, size_t ws_size,
                              hipStream_t stream) {
  const float* x  = (const float*)d_in[0];
  const float* Wr = (const float*)d_in[1];
  const float* Wi = (const float*)d_in[2];
  const float* Wj = (const float*)d_in[3];
  const float* Wk = (const float*)d_in[4];
  const float* br = (const float*)d_in[5];
  const float* bi = (const float*)d_in[6];
  const float* bj = (const float*)d_in[7];
  const float* bk = (const float*)d_in[8];
  float* out = (float*)d_out;

  const size_t WT_BYTES = (size_t)NDIM * KDIM * 2;  // 33.5 MB
  const size_t XB_BYTES = (size_t)MDIM * KDIM * 2;  // 67 MB

  if (ws_size < WT_BYTES) {
    dim3 g(NDIM / 256, MDIM);
    naive_q_kernel<<<g, 256, 0, stream>>>(x, Wr, Wi, Wj, Wk, br, bi, bj, bk, out);
    return;
  }
  uint16_t* wt = (uint16_t*)d_ws;
  build_wt2_kernel<<<dim3(16, 16, 4), 256, 0, stream>>>(Wr, Wi, Wj, Wk, wt);
  if (ws_size >= WT_BYTES + XB_BYTES) {
    uint16_t* xbp = wt + (size_t)NDIM * KDIM;
    cvt_x_kernel<<<(MDIM * (KDIM / 8)) / 256, 256, 0, stream>>>(x, xbp);
    hipError_t e0 = hipFuncSetAttribute(reinterpret_cast<const void*>(qgemm8_kernel<1>),
                                        hipFuncAttributeMaxDynamicSharedMemorySize, 131072);
    hipError_t e1 = hipFuncSetAttribute(reinterpret_cast<const void*>(qgemm8_kernel<0>),
                                        hipFuncAttributeMaxDynamicSharedMemorySize, 131072);
    if (e0 == hipSuccess && e1 == hipSuccess) {
      qgemm8_kernel<1><<<256, 512, 131072, stream>>>(xbp, wt, br, bi, bj, bk, out, 0);
      qgemm8_kernel<0><<<256, 512, 131072, stream>>>(xbp, wt, br, bi, bj, bk, out, 4096);
    } else {
      qgemm_kernel<<<2048, 256, 0, stream>>>(x, wt, br, bi, bj, bk, out);
    }
  } else {
    qgemm_kernel<<<2048, 256, 0, stream>>>(x, wt, br, bi, bj, bk, out);
  }
}